// Round 1
// baseline (7242.999 us; speedup 1.0000x reference)
//
#include <hip/hip_runtime.h>
#include <cmath>

using bf16 = __bf16;
typedef __bf16 bf16x8 __attribute__((ext_vector_type(8)));
typedef float f32x4 __attribute__((ext_vector_type(4)));

#define N_LAYER 12
#define EMB 768
#define E3 2304
#define FF 3072
#define SEQ 512
#define NB 8
#define BT 4096
#define NH 12
#define HD 64
#define VOC 60
#define DST 128
#define LDK 40  // 32 + 8 pad (16B) -> row stride 80B, conflict-free-ish

// ---------------- state scan ----------------
__global__ __launch_bounds__(1024)
void scan_kernel(const int* __restrict__ ids, const int* __restrict__ mul, int* __restrict__ pre)
{
    __shared__ int smul[VOC * VOC];
    __shared__ int sx[SEQ];
    __shared__ int chunk_end[16 * VOC];
    __shared__ int entry[17];
    int b = blockIdx.x;
    int tid = threadIdx.x;
    for (int i = tid; i < VOC * VOC; i += 1024) smul[i] = mul[i];
    for (int i = tid; i < SEQ; i += 1024) sx[i] = ids[b * SEQ + i];
    __syncthreads();
    if (tid < 16 * VOC) {
        int c = tid / VOC, s0 = tid % VOC;
        int s = s0;
        int base = c * 32;
        for (int j = 0; j < 32; j++) s = smul[sx[base + j] * VOC + s];
        chunk_end[c * VOC + s0] = s;
    }
    __syncthreads();
    if (tid == 0) {
        int s = 0; // ID_ID
        entry[0] = 0;
        for (int c = 0; c < 16; c++) { s = chunk_end[c * VOC + s]; entry[c + 1] = s; }
    }
    __syncthreads();
    if (tid < 16) {
        int c = tid;
        int s = entry[c];
        for (int j = 0; j < 32; j++) {
            int t = c * 32 + j;
            pre[b * SEQ + t] = s;
            s = smul[sx[t] * VOC + s];
        }
    }
}

// ---------------- state-emb projection table: pst[v][e] ----------------
__global__ __launch_bounds__(256)
void pst_kernel(const float* __restrict__ se, const float* __restrict__ w,
                const float* __restrict__ bias, float* __restrict__ pst)
{
    int v = blockIdx.x;
    int e = blockIdx.y * 256 + threadIdx.x;
    float acc = bias[e];
    for (int k = 0; k < DST; k++) acc += se[v * DST + k] * w[k * EMB + e];
    pst[v * EMB + e] = acc;
}

// ---------------- embedding ----------------
__global__ __launch_bounds__(256)
void embed_kernel(const int* __restrict__ ids, const int* __restrict__ pre,
                  const float* __restrict__ tok_emb, const float* __restrict__ pst,
                  const float* __restrict__ wpe, float* __restrict__ h)
{
    int idx = blockIdx.x * 256 + threadIdx.x;
    int tkn = idx / EMB, e = idx - tkn * EMB;
    int pos = tkn & (SEQ - 1);
    h[idx] = tok_emb[ids[tkn] * EMB + e] + pst[pre[tkn] * EMB + e] + wpe[pos * EMB + e];
}

// ---------------- weight transpose + fp32->bf16: W[K,N] -> WT[N,K] ----------------
__global__ __launch_bounds__(256)
void convw_kernel(const float* __restrict__ W, bf16* __restrict__ WT, int K, int N)
{
    __shared__ float tile[32][33];
    int kb = blockIdx.y * 32, nb = blockIdx.x * 32;
    const float* Wl = W + (size_t)blockIdx.z * K * N;
    bf16* WTl = WT + (size_t)blockIdx.z * K * N;
    int tx = threadIdx.x & 31, ty = threadIdx.x >> 5; // ty 0..7
    for (int i = ty; i < 32; i += 8) {
        int k = kb + i, n = nb + tx;
        if (k < K && n < N) tile[i][tx] = Wl[(size_t)k * N + n];
    }
    __syncthreads();
    for (int i = ty; i < 32; i += 8) {
        int n = nb + i, k = kb + tx;
        if (k < K && n < N) WTl[(size_t)n * K + k] = (bf16)tile[tx][i];
    }
}

// ---------------- layernorm: fp32 in -> bf16 out ----------------
__global__ __launch_bounds__(256)
void ln_kernel(const float* __restrict__ x, const float* __restrict__ g,
               const float* __restrict__ b, bf16* __restrict__ y)
{
    int t = blockIdx.x;
    const float* xr = x + (size_t)t * EMB;
    int tid = threadIdx.x;
    float vals[3];
    float s = 0.f, s2 = 0.f;
    for (int j = 0; j < 3; j++) {
        float xv = xr[tid + j * 256];
        vals[j] = xv; s += xv; s2 += xv * xv;
    }
    for (int o = 32; o > 0; o >>= 1) { s += __shfl_xor(s, o, 64); s2 += __shfl_xor(s2, o, 64); }
    __shared__ float ps[8];
    int wave = tid >> 6, lane = tid & 63;
    if (lane == 0) { ps[wave] = s; ps[4 + wave] = s2; }
    __syncthreads();
    s = ps[0] + ps[1] + ps[2] + ps[3];
    s2 = ps[4] + ps[5] + ps[6] + ps[7];
    float m = s * (1.0f / EMB);
    float var = s2 * (1.0f / EMB) - m * m;
    float inv = rsqrtf(var + 1e-5f);
    for (int j = 0; j < 3; j++) {
        int e = tid + j * 256;
        y[(size_t)t * EMB + e] = (bf16)((vals[j] - m) * inv * g[e] + b[e]);
    }
}

// ---------------- V transpose: qkv -> vT[bh][d][t] ----------------
__global__ __launch_bounds__(256)
void vtrans_kernel(const bf16* __restrict__ qkv, bf16* __restrict__ vT)
{
    int bh = blockIdx.y;
    int b = bh / NH, hh = bh - b * NH;
    int idx = blockIdx.x * 256 + threadIdx.x; // over 64*512
    int d = idx >> 9, t = idx & 511;
    vT[((size_t)bh * HD + d) * SEQ + t] = qkv[((size_t)(b * SEQ + t)) * E3 + 2 * EMB + hh * HD + d];
}

// ---------------- causal softmax, in-place on bf16 scores ----------------
__global__ __launch_bounds__(64)
void softmax_kernel(bf16* __restrict__ S)
{
    int t = blockIdx.x, bh = blockIdx.y;
    bf16* row = S + ((size_t)bh * SEQ + t) * SEQ;
    int lane = threadIdx.x;
    float v[8];
    float mx = -1e30f;
    for (int j = 0; j < 8; j++) {
        int c = lane + j * 64;
        float x = (c <= t) ? (float)row[c] * 0.125f : -1e30f;
        v[j] = x; mx = fmaxf(mx, x);
    }
    for (int o = 32; o > 0; o >>= 1) mx = fmaxf(mx, __shfl_xor(mx, o, 64));
    float sum = 0.f;
    for (int j = 0; j < 8; j++) {
        float e = (v[j] > -1e29f) ? __expf(v[j] - mx) : 0.0f;
        v[j] = e; sum += e;
    }
    for (int o = 32; o > 0; o >>= 1) sum += __shfl_xor(sum, o, 64);
    float inv = 1.0f / sum;
    for (int j = 0; j < 8; j++) {
        int c = lane + j * 64;
        row[c] = (bf16)(v[j] * inv);
    }
}

// ---------------- MFMA GEMM: C = A @ B^T(+bias), B given as [N][K] ----------------
// MODE 0: store bf16 (+bias)   MODE 1: bias+gelu -> bf16
// MODE 2: fp32 residual add    MODE 3: fp32 store (+bias)
template<int MODE>
__global__ __launch_bounds__(256)
void gemm_bt(const bf16* __restrict__ Ag, const bf16* __restrict__ Bg,
             const float* __restrict__ bias, bf16* __restrict__ Cb, float* __restrict__ Cf,
             int M, int N, int K, int lda, int ldb, int ldc,
             long long sAb, long long sAh, long long sBb, long long sBh,
             long long sCb, long long sCh)
{
    __shared__ bf16 lsA[128 * LDK];
    __shared__ bf16 lsB[128 * LDK];
    int z = blockIdx.z;
    int zb = z / NH, zh = z - zb * NH;
    Ag += zb * sAb + zh * sAh;
    Bg += zb * sBb + zh * sBh;
    long long coff = zb * sCb + zh * sCh;

    int m0 = blockIdx.y * 128, n0 = blockIdx.x * 128;
    int tid = threadIdx.x;
    int lane = tid & 63, wave = tid >> 6;
    int wm = (wave >> 1) * 64, wn = (wave & 1) * 64;
    int r = lane & 15, q = lane >> 4;

    f32x4 acc[4][4];
    for (int mi = 0; mi < 4; mi++)
        for (int ni = 0; ni < 4; ni++)
            for (int e = 0; e < 4; e++) acc[mi][ni][e] = 0.f;

    int srow = tid >> 2, sc = (tid & 3) * 8;
    for (int k0 = 0; k0 < K; k0 += 32) {
        for (int it = 0; it < 2; it++) {
            int row = srow + it * 64;
            bf16x8 av = *(const bf16x8*)(Ag + (size_t)(m0 + row) * lda + k0 + sc);
            *(bf16x8*)(lsA + row * LDK + sc) = av;
            int brow = n0 + row;
            bf16x8 bv;
            if (brow < N) bv = *(const bf16x8*)(Bg + (size_t)brow * ldb + k0 + sc);
            else for (int j = 0; j < 8; j++) bv[j] = (bf16)0.f;
            *(bf16x8*)(lsB + row * LDK + sc) = bv;
        }
        __syncthreads();
        bf16x8 af[4], bfr[4];
        for (int mi = 0; mi < 4; mi++) af[mi] = *(const bf16x8*)(lsA + (wm + mi * 16 + r) * LDK + q * 8);
        for (int ni = 0; ni < 4; ni++) bfr[ni] = *(const bf16x8*)(lsB + (wn + ni * 16 + r) * LDK + q * 8);
        for (int mi = 0; mi < 4; mi++)
            for (int ni = 0; ni < 4; ni++)
                acc[mi][ni] = __builtin_amdgcn_mfma_f32_16x16x32_bf16(af[mi], bfr[ni], acc[mi][ni], 0, 0, 0);
        __syncthreads();
    }

    for (int mi = 0; mi < 4; mi++) {
        for (int ni = 0; ni < 4; ni++) {
            int colg = n0 + wn + ni * 16 + r;
            if (colg >= N) continue;
            float bv = bias ? bias[colg] : 0.0f;
            for (int e = 0; e < 4; e++) {
                int rowg = m0 + wm + mi * 16 + q * 4 + e;
                if (rowg >= M) continue;
                float v = acc[mi][ni][e] + bv;
                size_t off = (size_t)coff + (size_t)rowg * ldc + colg;
                if constexpr (MODE == 0) {
                    Cb[off] = (bf16)v;
                } else if constexpr (MODE == 1) {
                    float g = 0.5f * v * (1.0f + tanhf(0.7978845608028654f * (v + 0.044715f * v * v * v)));
                    Cb[off] = (bf16)g;
                } else if constexpr (MODE == 2) {
                    Cf[off] += v;
                } else {
                    Cf[off] = v;
                }
            }
        }
    }
}

extern "C" void kernel_launch(void* const* d_in, const int* in_sizes, int n_in,
                              void* d_out, int out_size, void* d_ws, size_t ws_size,
                              hipStream_t stream)
{
    (void)in_sizes; (void)n_in; (void)out_size; (void)ws_size;
    const int*   input_ids    = (const int*)d_in[0];
    const int*   mul          = (const int*)d_in[1];
    const float* tok_emb      = (const float*)d_in[2];
    const float* state_emb    = (const float*)d_in[3];
    const float* state_proj_w = (const float*)d_in[4];
    const float* state_proj_b = (const float*)d_in[5];
    const float* wpe          = (const float*)d_in[6];
    const float* ln1_g        = (const float*)d_in[7];
    const float* ln1_b        = (const float*)d_in[8];
    const float* attn_w       = (const float*)d_in[9];
    const float* attn_b       = (const float*)d_in[10];
    const float* attn_proj_w  = (const float*)d_in[11];
    const float* attn_proj_b  = (const float*)d_in[12];
    const float* ln2_g        = (const float*)d_in[13];
    const float* ln2_b        = (const float*)d_in[14];
    const float* fc_w         = (const float*)d_in[15];
    const float* fc_b         = (const float*)d_in[16];
    const float* mlp_proj_w   = (const float*)d_in[17];
    const float* mlp_proj_b   = (const float*)d_in[18];
    const float* lnf_g        = (const float*)d_in[19];
    const float* lnf_b        = (const float*)d_in[20];
    const float* head_w       = (const float*)d_in[21];
    const float* head_b       = (const float*)d_in[22];
    float* out = (float*)d_out;

    char* ws = (char*)d_ws;
    size_t off = 0;
    auto alloc = [&](size_t bytes) -> char* {
        char* p = ws + off;
        off += (bytes + 255) & ~(size_t)255;
        return p;
    };
    bf16*  wT_attn = (bf16*)alloc((size_t)N_LAYER * E3 * EMB * 2);
    bf16*  wT_ap   = (bf16*)alloc((size_t)N_LAYER * EMB * EMB * 2);
    bf16*  wT_fc   = (bf16*)alloc((size_t)N_LAYER * FF * EMB * 2);
    bf16*  wT_mp   = (bf16*)alloc((size_t)N_LAYER * EMB * FF * 2);
    bf16*  wT_head = (bf16*)alloc((size_t)VOC * EMB * 2);
    float* pst     = (float*)alloc((size_t)VOC * EMB * 4);
    int*   pre     = (int*)alloc((size_t)BT * 4);
    float* h       = (float*)alloc((size_t)BT * EMB * 4);
    bf16*  xb      = (bf16*)alloc((size_t)BT * EMB * 2);
    bf16*  qkv     = (bf16*)alloc((size_t)BT * E3 * 2);
    bf16*  vT      = (bf16*)alloc((size_t)NB * NH * HD * SEQ * 2);
    bf16*  S       = (bf16*)alloc((size_t)NB * NH * SEQ * SEQ * 2);
    bf16*  o       = (bf16*)alloc((size_t)BT * EMB * 2);
    bf16*  fcout   = (bf16*)alloc((size_t)BT * FF * 2);

    // one-time per call: weight transpose+convert
    convw_kernel<<<dim3(E3 / 32, EMB / 32, N_LAYER), 256, 0, stream>>>(attn_w, wT_attn, EMB, E3);
    convw_kernel<<<dim3(EMB / 32, EMB / 32, N_LAYER), 256, 0, stream>>>(attn_proj_w, wT_ap, EMB, EMB);
    convw_kernel<<<dim3(FF / 32, EMB / 32, N_LAYER), 256, 0, stream>>>(fc_w, wT_fc, EMB, FF);
    convw_kernel<<<dim3(EMB / 32, FF / 32, N_LAYER), 256, 0, stream>>>(mlp_proj_w, wT_mp, FF, EMB);
    convw_kernel<<<dim3(2, EMB / 32, 1), 256, 0, stream>>>(head_w, wT_head, EMB, VOC);

    scan_kernel<<<NB, 1024, 0, stream>>>(input_ids, mul, pre);
    pst_kernel<<<dim3(VOC, 3), 256, 0, stream>>>(state_emb, state_proj_w, state_proj_b, pst);
    embed_kernel<<<(BT * EMB) / 256, 256, 0, stream>>>(input_ids, pre, tok_emb, pst, wpe, h);

    const long long TT = (long long)SEQ * SEQ;
    for (int l = 0; l < N_LAYER; l++) {
        ln_kernel<<<BT, 256, 0, stream>>>(h, ln1_g + l * EMB, ln1_b + l * EMB, xb);
        gemm_bt<0><<<dim3(E3 / 128, BT / 128, 1), 256, 0, stream>>>(
            xb, wT_attn + (size_t)l * E3 * EMB, attn_b + l * E3, qkv, nullptr,
            BT, E3, EMB, EMB, EMB, E3, 0, 0, 0, 0, 0, 0);
        vtrans_kernel<<<dim3(128, NB * NH), 256, 0, stream>>>(qkv, vT);
        // scores = Q @ K^T  (per head)
        gemm_bt<0><<<dim3(4, 4, NB * NH), 256, 0, stream>>>(
            qkv, qkv + EMB, nullptr, S, nullptr,
            SEQ, SEQ, HD, E3, E3, SEQ,
            (long long)SEQ * E3, HD, (long long)SEQ * E3, HD, NH * TT, TT);
        softmax_kernel<<<dim3(SEQ, NB * NH), 64, 0, stream>>>(S);
        // O = P @ V (per head) -> o[B,T,E]
        gemm_bt<0><<<dim3(1, 4, NB * NH), 256, 0, stream>>>(
            S, vT, nullptr, o, nullptr,
            SEQ, HD, SEQ, SEQ, SEQ, EMB,
            NH * TT, TT, (long long)NH * HD * SEQ, (long long)HD * SEQ,
            (long long)SEQ * EMB, HD);
        gemm_bt<2><<<dim3(EMB / 128, BT / 128, 1), 256, 0, stream>>>(
            o, wT_ap + (size_t)l * EMB * EMB, attn_proj_b + l * EMB, nullptr, h,
            BT, EMB, EMB, EMB, EMB, EMB, 0, 0, 0, 0, 0, 0);
        ln_kernel<<<BT, 256, 0, stream>>>(h, ln2_g + l * EMB, ln2_b + l * EMB, xb);
        gemm_bt<1><<<dim3(FF / 128, BT / 128, 1), 256, 0, stream>>>(
            xb, wT_fc + (size_t)l * FF * EMB, fc_b + l * FF, fcout, nullptr,
            BT, FF, EMB, EMB, EMB, FF, 0, 0, 0, 0, 0, 0);
        gemm_bt<2><<<dim3(EMB / 128, BT / 128, 1), 256, 0, stream>>>(
            fcout, wT_mp + (size_t)l * EMB * FF, mlp_proj_b + l * EMB, nullptr, h,
            BT, EMB, FF, FF, FF, EMB, 0, 0, 0, 0, 0, 0);
    }
    ln_kernel<<<BT, 256, 0, stream>>>(h, lnf_g, lnf_b, xb);
    gemm_bt<3><<<dim3(1, BT / 128, 1), 256, 0, stream>>>(
        xb, wT_head, head_b, nullptr, out,
        BT, VOC, EMB, EMB, EMB, VOC, 0, 0, 0, 0, 0, 0);
}

// Round 2
// 3788.058 us; speedup vs baseline: 1.9121x; 1.9121x over previous
//
#include <hip/hip_runtime.h>
#include <cmath>

using bf16 = __bf16;
typedef __bf16 bf16x8 __attribute__((ext_vector_type(8)));
typedef float f32x4 __attribute__((ext_vector_type(4)));

#define N_LAYER 12
#define EMB 768
#define E3 2304
#define FF 3072
#define SEQ 512
#define NB 8
#define BT 4096
#define NH 12
#define HD 64
#define VOC 60
#define DST 128

// ---------------- async global->LDS, 16B per lane ----------------
__device__ __forceinline__ void gll16(const bf16* g, bf16* l) {
    __builtin_amdgcn_global_load_lds(
        (const __attribute__((address_space(1))) void*)g,
        (__attribute__((address_space(3))) void*)l,
        16, 0, 0);
}

// ---------------- state scan ----------------
__global__ __launch_bounds__(1024)
void scan_kernel(const int* __restrict__ ids, const int* __restrict__ mul, int* __restrict__ pre)
{
    __shared__ int smul[VOC * VOC];
    __shared__ int sx[SEQ];
    __shared__ int chunk_end[16 * VOC];
    __shared__ int entry[17];
    int b = blockIdx.x;
    int tid = threadIdx.x;
    for (int i = tid; i < VOC * VOC; i += 1024) smul[i] = mul[i];
    for (int i = tid; i < SEQ; i += 1024) sx[i] = ids[b * SEQ + i];
    __syncthreads();
    if (tid < 16 * VOC) {
        int c = tid / VOC, s0 = tid % VOC;
        int s = s0;
        int base = c * 32;
        for (int j = 0; j < 32; j++) s = smul[sx[base + j] * VOC + s];
        chunk_end[c * VOC + s0] = s;
    }
    __syncthreads();
    if (tid == 0) {
        int s = 0; // ID_ID
        entry[0] = 0;
        for (int c = 0; c < 16; c++) { s = chunk_end[c * VOC + s]; entry[c + 1] = s; }
    }
    __syncthreads();
    if (tid < 16) {
        int c = tid;
        int s = entry[c];
        for (int j = 0; j < 32; j++) {
            int t = c * 32 + j;
            pre[b * SEQ + t] = s;
            s = smul[sx[t] * VOC + s];
        }
    }
}

// ---------------- state-emb projection table: pst[v][e] ----------------
__global__ __launch_bounds__(256)
void pst_kernel(const float* __restrict__ se, const float* __restrict__ w,
                const float* __restrict__ bias, float* __restrict__ pst)
{
    int v = blockIdx.x;
    int e = blockIdx.y * 256 + threadIdx.x;
    float acc = bias[e];
    for (int k = 0; k < DST; k++) acc += se[v * DST + k] * w[k * EMB + e];
    pst[v * EMB + e] = acc;
}

// ---------------- embedding ----------------
__global__ __launch_bounds__(256)
void embed_kernel(const int* __restrict__ ids, const int* __restrict__ pre,
                  const float* __restrict__ tok_emb, const float* __restrict__ pst,
                  const float* __restrict__ wpe, float* __restrict__ h)
{
    int idx = blockIdx.x * 256 + threadIdx.x;
    int tkn = idx / EMB, e = idx - tkn * EMB;
    int pos = tkn & (SEQ - 1);
    h[idx] = tok_emb[ids[tkn] * EMB + e] + pst[pre[tkn] * EMB + e] + wpe[pos * EMB + e];
}

// ---------------- weight transpose + fp32->bf16: W[K,N] -> WT[N,K] ----------------
__global__ __launch_bounds__(256)
void convw_kernel(const float* __restrict__ W, bf16* __restrict__ WT, int K, int N)
{
    __shared__ float tile[32][33];
    int kb = blockIdx.y * 32, nb = blockIdx.x * 32;
    const float* Wl = W + (size_t)blockIdx.z * K * N;
    bf16* WTl = WT + (size_t)blockIdx.z * K * N;
    int tx = threadIdx.x & 31, ty = threadIdx.x >> 5; // ty 0..7
    for (int i = ty; i < 32; i += 8) {
        int k = kb + i, n = nb + tx;
        if (k < K && n < N) tile[i][tx] = Wl[(size_t)k * N + n];
    }
    __syncthreads();
    for (int i = ty; i < 32; i += 8) {
        int n = nb + i, k = kb + tx;
        if (k < K && n < N) WTl[(size_t)n * K + k] = (bf16)tile[tx][i];
    }
}

// ---------------- layernorm: fp32 in -> bf16 out ----------------
__global__ __launch_bounds__(256)
void ln_kernel(const float* __restrict__ x, const float* __restrict__ g,
               const float* __restrict__ b, bf16* __restrict__ y)
{
    int t = blockIdx.x;
    const float* xr = x + (size_t)t * EMB;
    int tid = threadIdx.x;
    float vals[3];
    float s = 0.f, s2 = 0.f;
    for (int j = 0; j < 3; j++) {
        float xv = xr[tid + j * 256];
        vals[j] = xv; s += xv; s2 += xv * xv;
    }
    for (int o = 32; o > 0; o >>= 1) { s += __shfl_xor(s, o, 64); s2 += __shfl_xor(s2, o, 64); }
    __shared__ float ps[8];
    int wave = tid >> 6, lane = tid & 63;
    if (lane == 0) { ps[wave] = s; ps[4 + wave] = s2; }
    __syncthreads();
    s = ps[0] + ps[1] + ps[2] + ps[3];
    s2 = ps[4] + ps[5] + ps[6] + ps[7];
    float m = s * (1.0f / EMB);
    float var = s2 * (1.0f / EMB) - m * m;
    float inv = rsqrtf(var + 1e-5f);
    for (int j = 0; j < 3; j++) {
        int e = tid + j * 256;
        y[(size_t)t * EMB + e] = (bf16)((vals[j] - m) * inv * g[e] + b[e]);
    }
}

// ---------------- V transpose: qkv -> vT[bh][d][t] ----------------
__global__ __launch_bounds__(256)
void vtrans_kernel(const bf16* __restrict__ qkv, bf16* __restrict__ vT)
{
    int bh = blockIdx.y;
    int b = bh / NH, hh = bh - b * NH;
    int idx = blockIdx.x * 256 + threadIdx.x; // over 64*512
    int d = idx >> 9, t = idx & 511;
    vT[((size_t)bh * HD + d) * SEQ + t] = qkv[((size_t)(b * SEQ + t)) * E3 + 2 * EMB + hh * HD + d];
}

// ---------------- causal softmax, in-place on bf16 scores ----------------
__global__ __launch_bounds__(64)
void softmax_kernel(bf16* __restrict__ S)
{
    int t = blockIdx.x, bh = blockIdx.y;
    bf16* row = S + ((size_t)bh * SEQ + t) * SEQ;
    int lane = threadIdx.x;
    float v[8];
    float mx = -1e30f;
    for (int j = 0; j < 8; j++) {
        int c = lane + j * 64;
        float x = (c <= t) ? (float)row[c] * 0.125f : -1e30f;
        v[j] = x; mx = fmaxf(mx, x);
    }
    for (int o = 32; o > 0; o >>= 1) mx = fmaxf(mx, __shfl_xor(mx, o, 64));
    float sum = 0.f;
    for (int j = 0; j < 8; j++) {
        float e = (v[j] > -1e29f) ? __expf(v[j] - mx) : 0.0f;
        v[j] = e; sum += e;
    }
    for (int o = 32; o > 0; o >>= 1) sum += __shfl_xor(sum, o, 64);
    float inv = 1.0f / sum;
    for (int j = 0; j < 8; j++) {
        int c = lane + j * 64;
        row[c] = (bf16)(v[j] * inv);
    }
}

// ---------------- MFMA GEMM (m97 structure): C = A @ B^T(+bias), B given as [N][K] ----------------
// MODE 0: store bf16 (+bias)   MODE 1: bias+gelu -> bf16
// MODE 2: fp32 residual add    MODE 3: fp32 store (+bias), scalar (unaligned ldc)
template<int MODE>
__global__ __launch_bounds__(256)
void gemm_bt(const bf16* __restrict__ Ag, const bf16* __restrict__ Bg,
             const float* __restrict__ bias, bf16* __restrict__ Cb, float* __restrict__ Cf,
             int M, int N, int K, int lda, int ldb, int ldc,
             long long sAb, long long sAh, long long sBb, long long sBh,
             long long sCb, long long sCh)
{
    __shared__ union { bf16 ab[2][128 * 32]; float st[4][16 * 64]; } sm;
    int z = blockIdx.z;
    int zb = z / NH, zh = z - zb * NH;
    Ag += zb * sAb + zh * sAh;
    Bg += zb * sBb + zh * sBh;
    long long coff = zb * sCb + zh * sCh;

    int m0 = blockIdx.y * 128, n0 = blockIdx.x * 128;
    int tid = threadIdx.x, lane = tid & 63, wave = tid >> 6;
    int wm = (wave >> 1) * 64, wn = (wave & 1) * 64;
    int r = lane & 15, q = lane >> 4;

    f32x4 acc[4][4];
    for (int mi = 0; mi < 4; mi++)
        for (int ni = 0; ni < 4; ni++)
            for (int e = 0; e < 4; e++) acc[mi][ni][e] = 0.f;

    bf16* la = sm.ab[0];
    bf16* lb = sm.ab[1];
    // staging: wave w deposits rows [w*16, w*16+16) and [w*16+64, w*16+80);
    // lane i -> row base+i/4, col (i&3)*8  (matches lane*16B contiguous LDS)
    int srow = wave * 16 + (lane >> 2);
    int scol = (lane & 3) * 8;
    const bf16* pA = Ag + (size_t)(m0 + srow) * lda + scol;
    const bf16* pB = Bg + (size_t)(n0 + srow) * ldb + scol;
    bf16* lA0 = la + (wave * 16) * 32;
    bf16* lA1 = la + (wave * 16 + 64) * 32;
    bf16* lB0 = lb + (wave * 16) * 32;
    bf16* lB1 = lb + (wave * 16 + 64) * 32;
    size_t stepA = (size_t)64 * lda, stepB = (size_t)64 * ldb;

    for (int k0 = 0; k0 < K; k0 += 32) {
        gll16(pA + k0, lA0);
        gll16(pA + k0 + stepA, lA1);
        gll16(pB + k0, lB0);
        gll16(pB + k0 + stepB, lB1);
        __syncthreads();
        bf16x8 af[4], bq[4];
        for (int mi = 0; mi < 4; mi++) af[mi] = *(const bf16x8*)(la + (wm + mi * 16 + r) * 32 + q * 8);
        for (int ni = 0; ni < 4; ni++) bq[ni] = *(const bf16x8*)(lb + (wn + ni * 16 + r) * 32 + q * 8);
        for (int mi = 0; mi < 4; mi++)
            for (int ni = 0; ni < 4; ni++)
                acc[mi][ni] = __builtin_amdgcn_mfma_f32_16x16x32_bf16(af[mi], bq[ni], acc[mi][ni], 0, 0, 0);
        __syncthreads();
    }

    if constexpr (MODE == 3) {
        // scalar fp32 store (small N, unaligned ldc)
        for (int mi = 0; mi < 4; mi++) {
            for (int ni = 0; ni < 4; ni++) {
                int colg = n0 + wn + ni * 16 + r;
                if (colg >= N) continue;
                float bv = bias ? bias[colg] : 0.0f;
                for (int e = 0; e < 4; e++) {
                    int rowg = m0 + wm + mi * 16 + q * 4 + e;
                    if (rowg >= M) continue;
                    Cf[(size_t)coff + (size_t)rowg * ldc + colg] = acc[mi][ni][e] + bv;
                }
            }
        }
        return;
    }

    // vectorized epilogue: per-wave 16x64 LDS transpose -> coalesced 16B/lane writes
    float* st = sm.st[wave];
    bool wvalid = (n0 + wn) < N;   // PV gemm: N=64, right half-tile unused
    for (int mi = 0; mi < 4; mi++) {
        if (wvalid) {
            for (int ni = 0; ni < 4; ni++)
                for (int e = 0; e < 4; e++)
                    st[(q * 4 + e) * 64 + ni * 16 + r] = acc[mi][ni][e];
        }
        asm volatile("s_waitcnt lgkmcnt(0)" ::: "memory");
        if (wvalid) {
            for (int it = 0; it < 2; it++) {
                int task = lane + it * 64;      // 128 tasks: 16 rows x 8 col-chunks
                int row = task >> 3, cc = (task & 7) * 8;
                f32x4 v0 = *(const f32x4*)(st + row * 64 + cc);
                f32x4 v1 = *(const f32x4*)(st + row * 64 + cc + 4);
                int colg = n0 + wn + cc;
                int rowg = m0 + wm + mi * 16 + row;
                if (bias) {
                    f32x4 b0 = *(const f32x4*)(bias + colg);
                    f32x4 b1 = *(const f32x4*)(bias + colg + 4);
                    v0 += b0; v1 += b1;
                }
                size_t off = (size_t)coff + (size_t)rowg * ldc + colg;
                if constexpr (MODE == 0) {
                    bf16x8 pk;
                    for (int j = 0; j < 4; j++) { pk[j] = (bf16)v0[j]; pk[4 + j] = (bf16)v1[j]; }
                    *(bf16x8*)(Cb + off) = pk;
                } else if constexpr (MODE == 1) {
                    float w[8];
                    for (int j = 0; j < 4; j++) { w[j] = v0[j]; w[4 + j] = v1[j]; }
                    bf16x8 pk;
                    for (int j = 0; j < 8; j++) {
                        float x = w[j];
                        float gx = 0.5f * x * (1.0f + tanhf(0.7978845608028654f * (x + 0.044715f * x * x * x)));
                        pk[j] = (bf16)gx;
                    }
                    *(bf16x8*)(Cb + off) = pk;
                } else { // MODE 2: fp32 residual RMW, two float4
                    f32x4* hp = (f32x4*)(Cf + off);
                    f32x4 h0 = hp[0], h1 = hp[1];
                    hp[0] = h0 + v0;
                    hp[1] = h1 + v1;
                }
            }
        }
        asm volatile("s_waitcnt lgkmcnt(0)" ::: "memory");
    }
}

extern "C" void kernel_launch(void* const* d_in, const int* in_sizes, int n_in,
                              void* d_out, int out_size, void* d_ws, size_t ws_size,
                              hipStream_t stream)
{
    (void)in_sizes; (void)n_in; (void)out_size; (void)ws_size;
    const int*   input_ids    = (const int*)d_in[0];
    const int*   mul          = (const int*)d_in[1];
    const float* tok_emb      = (const float*)d_in[2];
    const float* state_emb    = (const float*)d_in[3];
    const float* state_proj_w = (const float*)d_in[4];
    const float* state_proj_b = (const float*)d_in[5];
    const float* wpe          = (const float*)d_in[6];
    const float* ln1_g        = (const float*)d_in[7];
    const float* ln1_b        = (const float*)d_in[8];
    const float* attn_w       = (const float*)d_in[9];
    const float* attn_b       = (const float*)d_in[10];
    const float* attn_proj_w  = (const float*)d_in[11];
    const float* attn_proj_b  = (const float*)d_in[12];
    const float* ln2_g        = (const float*)d_in[13];
    const float* ln2_b        = (const float*)d_in[14];
    const float* fc_w         = (const float*)d_in[15];
    const float* fc_b         = (const float*)d_in[16];
    const float* mlp_proj_w   = (const float*)d_in[17];
    const float* mlp_proj_b   = (const float*)d_in[18];
    const float* lnf_g        = (const float*)d_in[19];
    const float* lnf_b        = (const float*)d_in[20];
    const float* head_w       = (const float*)d_in[21];
    const float* head_b       = (const float*)d_in[22];
    float* out = (float*)d_out;

    char* ws = (char*)d_ws;
    size_t off = 0;
    auto alloc = [&](size_t bytes) -> char* {
        char* p = ws + off;
        off += (bytes + 255) & ~(size_t)255;
        return p;
    };
    bf16*  wT_attn = (bf16*)alloc((size_t)N_LAYER * E3 * EMB * 2);
    bf16*  wT_ap   = (bf16*)alloc((size_t)N_LAYER * EMB * EMB * 2);
    bf16*  wT_fc   = (bf16*)alloc((size_t)N_LAYER * FF * EMB * 2);
    bf16*  wT_mp   = (bf16*)alloc((size_t)N_LAYER * EMB * FF * 2);
    bf16*  wT_head = (bf16*)alloc((size_t)VOC * EMB * 2);
    float* pst     = (float*)alloc((size_t)VOC * EMB * 4);
    int*   pre     = (int*)alloc((size_t)BT * 4);
    float* h       = (float*)alloc((size_t)BT * EMB * 4);
    bf16*  xb      = (bf16*)alloc((size_t)BT * EMB * 2);
    bf16*  qkv     = (bf16*)alloc((size_t)BT * E3 * 2);
    bf16*  vT      = (bf16*)alloc((size_t)NB * NH * HD * SEQ * 2);
    bf16*  S       = (bf16*)alloc((size_t)NB * NH * SEQ * SEQ * 2);
    bf16*  o       = (bf16*)alloc((size_t)BT * EMB * 2);
    bf16*  fcout   = (bf16*)alloc((size_t)BT * FF * 2);

    // one-time per call: weight transpose+convert
    convw_kernel<<<dim3(E3 / 32, EMB / 32, N_LAYER), 256, 0, stream>>>(attn_w, wT_attn, EMB, E3);
    convw_kernel<<<dim3(EMB / 32, EMB / 32, N_LAYER), 256, 0, stream>>>(attn_proj_w, wT_ap, EMB, EMB);
    convw_kernel<<<dim3(FF / 32, EMB / 32, N_LAYER), 256, 0, stream>>>(fc_w, wT_fc, EMB, FF);
    convw_kernel<<<dim3(EMB / 32, FF / 32, N_LAYER), 256, 0, stream>>>(mlp_proj_w, wT_mp, FF, EMB);
    convw_kernel<<<dim3(2, EMB / 32, 1), 256, 0, stream>>>(head_w, wT_head, EMB, VOC);

    scan_kernel<<<NB, 1024, 0, stream>>>(input_ids, mul, pre);
    pst_kernel<<<dim3(VOC, 3), 256, 0, stream>>>(state_emb, state_proj_w, state_proj_b, pst);
    embed_kernel<<<(BT * EMB) / 256, 256, 0, stream>>>(input_ids, pre, tok_emb, pst, wpe, h);

    const long long TT = (long long)SEQ * SEQ;
    for (int l = 0; l < N_LAYER; l++) {
        ln_kernel<<<BT, 256, 0, stream>>>(h, ln1_g + l * EMB, ln1_b + l * EMB, xb);
        gemm_bt<0><<<dim3(E3 / 128, BT / 128, 1), 256, 0, stream>>>(
            xb, wT_attn + (size_t)l * E3 * EMB, attn_b + l * E3, qkv, nullptr,
            BT, E3, EMB, EMB, EMB, E3, 0, 0, 0, 0, 0, 0);
        vtrans_kernel<<<dim3(128, NB * NH), 256, 0, stream>>>(qkv, vT);
        // scores = Q @ K^T  (per head)
        gemm_bt<0><<<dim3(4, 4, NB * NH), 256, 0, stream>>>(
            qkv, qkv + EMB, nullptr, S, nullptr,
            SEQ, SEQ, HD, E3, E3, SEQ,
            (long long)SEQ * E3, HD, (long long)SEQ * E3, HD, NH * TT, TT);
        softmax_kernel<<<dim3(SEQ, NB * NH), 64, 0, stream>>>(S);
        // O = P @ V (per head) -> o[B,T,E]
        gemm_bt<0><<<dim3(1, 4, NB * NH), 256, 0, stream>>>(
            S, vT, nullptr, o, nullptr,
            SEQ, HD, SEQ, SEQ, SEQ, EMB,
            NH * TT, TT, (long long)NH * HD * SEQ, (long long)HD * SEQ,
            (long long)SEQ * EMB, HD);
        gemm_bt<2><<<dim3(EMB / 128, BT / 128, 1), 256, 0, stream>>>(
            o, wT_ap + (size_t)l * EMB * EMB, attn_proj_b + l * EMB, nullptr, h,
            BT, EMB, EMB, EMB, EMB, EMB, 0, 0, 0, 0, 0, 0);
        ln_kernel<<<BT, 256, 0, stream>>>(h, ln2_g + l * EMB, ln2_b + l * EMB, xb);
        gemm_bt<1><<<dim3(FF / 128, BT / 128, 1), 256, 0, stream>>>(
            xb, wT_fc + (size_t)l * FF * EMB, fc_b + l * FF, fcout, nullptr,
            BT, FF, EMB, EMB, EMB, FF, 0, 0, 0, 0, 0, 0);
        gemm_bt<2><<<dim3(EMB / 128, BT / 128, 1), 256, 0, stream>>>(
            fcout, wT_mp + (size_t)l * EMB * FF, mlp_proj_b + l * EMB, nullptr, h,
            BT, EMB, FF, FF, FF, EMB, 0, 0, 0, 0, 0, 0);
    }
    ln_kernel<<<BT, 256, 0, stream>>>(h, lnf_g, lnf_b, xb);
    gemm_bt<3><<<dim3(1, BT / 128, 1), 256, 0, stream>>>(
        xb, wT_head, head_b, nullptr, out,
        BT, VOC, EMB, EMB, EMB, VOC, 0, 0, 0, 0, 0, 0);
}